// Round 9
// baseline (356.017 us; speedup 1.0000x reference)
//
#include <hip/hip_runtime.h>
#include <hip/hip_bf16.h>

#define NN 100000
#define NE 1200000
#define IND 128
#define HID 64
#define NC 5
#define NG 128
#define NB 391    // ceil(NN/256)
#define GB 1172   // bucket blocks (GB*256*4 >= NE)
#define G1 3125   // gemm1 blocks (NN/32)

static __device__ __forceinline__ float bf2f(unsigned short u) {
    union { unsigned int i; float f; } x;
    x.i = (unsigned int)u << 16;
    return x.f;
}
static __device__ __forceinline__ unsigned short f2bf(float f) {
    union { float f; unsigned int i; } x;
    x.f = f;
    unsigned int r = (x.i + 0x7fffu + ((x.i >> 16) & 1u)) >> 16;  // RNE
    return (unsigned short)r;
}

// ---------------- CSR build ----------------
__global__ __launch_bounds__(256) void k_hist(const int* __restrict__ dst, int* __restrict__ cnt,
                                              int* __restrict__ rank) {
    int e = blockIdx.x * 256 + threadIdx.x;
    if (e < NE) rank[e] = atomicAdd(&cnt[dst[e]], 1);
}

// scan over cnt + dinv = rsqrt(cnt+1) fused
__global__ __launch_bounds__(256) void k_scan1(const int* __restrict__ cnt, int* __restrict__ exc,
                                               int* __restrict__ bsum, float* __restrict__ dinv) {
    __shared__ int lds[256];
    int tid = threadIdx.x;
    int i = blockIdx.x * 256 + tid;
    int v = (i < NN) ? cnt[i] : 0;
    lds[tid] = v;
    __syncthreads();
    for (int off = 1; off < 256; off <<= 1) {
        int t = (tid >= off) ? lds[tid - off] : 0;
        __syncthreads();
        lds[tid] += t;
        __syncthreads();
    }
    if (i < NN) {
        exc[i] = lds[tid] - v;
        dinv[i] = rsqrtf((float)v + 1.0f);
    }
    if (tid == 255) bsum[blockIdx.x] = lds[255];
}

// merged scan2+scan3: each block computes prefix(bsum[0..blockIdx.x)) by reduction
__global__ __launch_bounds__(256) void k_scan23(const int* __restrict__ exc, const int* __restrict__ bsum,
                                                int* __restrict__ row_ptr) {
    __shared__ int lds[256];
    int tid = threadIdx.x;
    int me = blockIdx.x;
    int v = 0;
    if (tid < me) v = bsum[tid];
    if (tid + 256 < me) v += bsum[tid + 256];
    lds[tid] = v;
    __syncthreads();
    for (int off = 128; off > 0; off >>= 1) {
        if (tid < off) lds[tid] += lds[tid + off];
        __syncthreads();
    }
    int base = lds[0];
    int i = me * 256 + tid;
    if (i < NN) row_ptr[i] = exc[i] + base;
    if (i == 0) row_ptr[NN] = NE;
}

// ---------------- fused grid: bucket | layer-1 GEMM | bounds ----------------
__global__ __launch_bounds__(256) void k_fused1(
    const float* __restrict__ X, const float* __restrict__ W,
    const float* __restrict__ dinv, unsigned short* __restrict__ out_bf,
    const int* __restrict__ src, const int* __restrict__ dst,
    const int* __restrict__ row_ptr, const int* __restrict__ rank,
    int* __restrict__ src_sorted,
    const int* __restrict__ batch, int* __restrict__ start)
{
    __shared__ float lds[IND * HID + 32 * IND];  // 48 KB (gemm1 segment only)
    int tid = threadIdx.x;

    if (blockIdx.x < GB) {
        // ---- bucket: atomic-free scatter, 4 independent edges/thread ----
        int t = blockIdx.x * 256 + tid;
        const int T = GB * 256;
#pragma unroll
        for (int u = 0; u < 4; ++u) {
            int e = t + u * T;
            if (e < NE) src_sorted[row_ptr[dst[e]] + rank[e]] = src[e];
        }
        return;
    }
    if (blockIdx.x >= GB + G1) {
        // ---- bounds: segment starts from sorted batch ids ----
        int i = (blockIdx.x - GB - G1) * 256 + tid;
        if (i >= NN) return;
        int b = batch[i];
        if (i == 0) {
            for (int g = 0; g <= b; ++g) start[g] = 0;
        } else {
            int p = batch[i - 1];
            for (int g = p + 1; g <= b; ++g) start[g] = i;
        }
        if (i == NN - 1) {
            for (int g = b + 1; g <= NG; ++g) start[g] = NN;
        }
        return;
    }

    // ---- gemm1: out_bf[n][j] = bf16(dinv[n] * sum_k X[n][k]*W1[k][j]) ----
    float* Wl = lds;             // [128][64]
    float* xl = lds + IND * HID; // [32][128]
    int n0 = (blockIdx.x - GB) * 32;
    int c = tid & 31;
    int s = tid >> 5;

    {
        const float4* Wg = (const float4*)W;
        float4* Wl4 = (float4*)Wl;
#pragma unroll
        for (int i = 0; i < IND * 16 / 256; ++i) Wl4[i * 256 + tid] = Wg[i * 256 + tid];
    }
    {
        const float4* Xg = (const float4*)X;
        float4* xl4 = (float4*)xl;
        const float4 z = {0.f, 0.f, 0.f, 0.f};
#pragma unroll
        for (int i = 0; i < 32 * IND / 4 / 256; ++i) {
            int idx = i * 256 + tid;
            int node = n0 + idx / (IND / 4);
            xl4[idx] = (node < NN) ? Xg[(size_t)n0 * (IND / 4) + idx] : z;
        }
    }
    __syncthreads();

    float acc[4][2];
#pragma unroll
    for (int r = 0; r < 4; ++r) { acc[r][0] = 0.f; acc[r][1] = 0.f; }

#pragma unroll 4
    for (int k0 = 0; k0 < IND; k0 += 4) {
        float4 xv[4];
#pragma unroll
        for (int r = 0; r < 4; ++r) xv[r] = *(const float4*)&xl[(s * 4 + r) * IND + k0];
#pragma unroll
        for (int kk = 0; kk < 4; ++kk) {
            float w0 = Wl[(k0 + kk) * HID + c];
            float w1 = Wl[(k0 + kk) * HID + c + 32];
#pragma unroll
            for (int r = 0; r < 4; ++r) {
                float xe = (kk == 0) ? xv[r].x : (kk == 1) ? xv[r].y : (kk == 2) ? xv[r].z : xv[r].w;
                acc[r][0] = fmaf(xe, w0, acc[r][0]);
                acc[r][1] = fmaf(xe, w1, acc[r][1]);
            }
        }
    }

#pragma unroll
    for (int r = 0; r < 4; ++r) {
        int n = n0 + s * 4 + r;
        if (n < NN) {
            float dn = dinv[n];
            out_bf[n * HID + c]      = f2bf(acc[r][0] * dn);
            out_bf[n * HID + c + 32] = f2bf(acc[r][1] * dn);
        }
    }
}

// ---------------- aggregate v3: 2 edges per VMEM instruction ----------------
// Wave handles one node. Lanes 0-31 = edge A (2 bf16/lane), lanes 32-63 = edge B.
// outb[n][j] = bf16( relu(dinv[n]*(hW[n][j] + sum_src hW[src][j]) + b[j]) )
__global__ __launch_bounds__(256) void k_aggregate(const unsigned short* __restrict__ hW,
                                                   const int* __restrict__ srcs,
                                                   const int* __restrict__ row_ptr,
                                                   const float* __restrict__ dinv,
                                                   const float* __restrict__ b,
                                                   unsigned short* __restrict__ outb) {
    const unsigned int* __restrict__ hW4 = (const unsigned int*)hW;  // row stride 32 uints
    int tid = threadIdx.x;
    int lane = tid & 63;
    int half = lane >> 5;
    int l = lane & 31;
    int n = blockIdx.x * 4 + (tid >> 6);  // NN = 25000*4, always valid

    // self term (half 0 only, so the cross-half reduce doesn't double it)
    unsigned int su = hW4[(size_t)n * 32 + l];
    float acc0 = half ? 0.f : bf2f((unsigned short)(su & 0xffff));
    float acc1 = half ? 0.f : bf2f((unsigned short)(su >> 16));

    int e = row_ptr[n];
    int end = row_ptr[n + 1];

    // 8 edges / iter: 4 gather insts in flight
    for (; e + 7 < end; e += 8) {
        int s0 = srcs[e],     s1 = srcs[e + 1], s2 = srcs[e + 2], s3 = srcs[e + 3];
        int s4 = srcs[e + 4], s5 = srcs[e + 5], s6 = srcs[e + 6], s7 = srcs[e + 7];
        int sa = half ? s1 : s0;
        int sb = half ? s3 : s2;
        int sc = half ? s5 : s4;
        int sd = half ? s7 : s6;
        unsigned int ua = hW4[(size_t)sa * 32 + l];
        unsigned int ub = hW4[(size_t)sb * 32 + l];
        unsigned int uc = hW4[(size_t)sc * 32 + l];
        unsigned int ud = hW4[(size_t)sd * 32 + l];
        acc0 += (bf2f((unsigned short)(ua & 0xffff)) + bf2f((unsigned short)(ub & 0xffff)))
              + (bf2f((unsigned short)(uc & 0xffff)) + bf2f((unsigned short)(ud & 0xffff)));
        acc1 += (bf2f((unsigned short)(ua >> 16)) + bf2f((unsigned short)(ub >> 16)))
              + (bf2f((unsigned short)(uc >> 16)) + bf2f((unsigned short)(ud >> 16)));
    }
    // 4 edges
    if (e + 3 < end) {
        int s0 = srcs[e], s1 = srcs[e + 1], s2 = srcs[e + 2], s3 = srcs[e + 3];
        int sa = half ? s1 : s0;
        int sb = half ? s3 : s2;
        unsigned int ua = hW4[(size_t)sa * 32 + l];
        unsigned int ub = hW4[(size_t)sb * 32 + l];
        acc0 += bf2f((unsigned short)(ua & 0xffff)) + bf2f((unsigned short)(ub & 0xffff));
        acc1 += bf2f((unsigned short)(ua >> 16)) + bf2f((unsigned short)(ub >> 16));
        e += 4;
    }
    // 2 edges
    if (e + 1 < end) {
        int s0 = srcs[e], s1 = srcs[e + 1];
        int sa = half ? s1 : s0;
        unsigned int ua = hW4[(size_t)sa * 32 + l];
        acc0 += bf2f((unsigned short)(ua & 0xffff));
        acc1 += bf2f((unsigned short)(ua >> 16));
        e += 2;
    }
    // last odd edge: half 0 only
    if (e < end && half == 0) {
        int s0 = srcs[e];
        unsigned int ua = hW4[(size_t)s0 * 32 + l];
        acc0 += bf2f((unsigned short)(ua & 0xffff));
        acc1 += bf2f((unsigned short)(ua >> 16));
    }

    // cross-half reduce: all lanes end with the full sums
    acc0 += __shfl_xor(acc0, 32, 64);
    acc1 += __shfl_xor(acc1, 32, 64);

    if (half == 0) {
        float dn = dinv[n];
        float v0 = fmaxf(fmaf(dn, acc0, b[2 * l]), 0.0f);
        float v1 = fmaxf(fmaf(dn, acc1, b[2 * l + 1]), 0.0f);
        unsigned int p = (unsigned int)f2bf(v0) | ((unsigned int)f2bf(v1) << 16);
        ((unsigned int*)outb)[(size_t)n * 32 + l] = p;
    }
}

// ---------------- GEMM layers 2/3: bf16 in, bf16 out ----------------
__global__ __launch_bounds__(256) void k_gemm_bf(const unsigned short* __restrict__ X,
                                                 const float* __restrict__ W,
                                                 const float* __restrict__ dinv,
                                                 unsigned short* __restrict__ outb) {
    __shared__ float Wl[HID * HID];  // 16 KB
    __shared__ float xl[64 * HID];   // 16 KB
    int tid = threadIdx.x;
    int n0 = blockIdx.x * 64;

    {
        const float4* Wg = (const float4*)W;
        float4* Wl4 = (float4*)Wl;
#pragma unroll
        for (int i = 0; i < HID * HID / 4 / 256; ++i) Wl4[i * 256 + tid] = Wg[i * 256 + tid];
    }
    {
        const uint4* Xg = (const uint4*)X;
#pragma unroll
        for (int i = 0; i < 2; ++i) {
            int idx = i * 256 + tid;      // 0..511
            int ln = idx >> 3;            // local node
            int k0 = (idx & 7) * 8;
            int node = n0 + ln;
            float f[8];
            if (node < NN) {
                uint4 u = Xg[(size_t)n0 * 8 + idx];
                f[0] = bf2f((unsigned short)(u.x & 0xffff));
                f[1] = bf2f((unsigned short)(u.x >> 16));
                f[2] = bf2f((unsigned short)(u.y & 0xffff));
                f[3] = bf2f((unsigned short)(u.y >> 16));
                f[4] = bf2f((unsigned short)(u.z & 0xffff));
                f[5] = bf2f((unsigned short)(u.z >> 16));
                f[6] = bf2f((unsigned short)(u.w & 0xffff));
                f[7] = bf2f((unsigned short)(u.w >> 16));
            } else {
#pragma unroll
                for (int q = 0; q < 8; ++q) f[q] = 0.f;
            }
#pragma unroll
            for (int q = 0; q < 8; ++q) xl[ln * HID + k0 + q] = f[q];
        }
    }
    __syncthreads();

    int c = tid & 31;
    int s = tid >> 5;
    float acc[8][2];
#pragma unroll
    for (int r = 0; r < 8; ++r) { acc[r][0] = 0.f; acc[r][1] = 0.f; }

#pragma unroll 4
    for (int k0 = 0; k0 < HID; k0 += 4) {
        float4 xv[8];
#pragma unroll
        for (int r = 0; r < 8; ++r) xv[r] = *(const float4*)&xl[(s * 8 + r) * HID + k0];
#pragma unroll
        for (int kk = 0; kk < 4; ++kk) {
            float w0 = Wl[(k0 + kk) * HID + c];
            float w1 = Wl[(k0 + kk) * HID + c + 32];
#pragma unroll
            for (int r = 0; r < 8; ++r) {
                float xe = (kk == 0) ? xv[r].x : (kk == 1) ? xv[r].y : (kk == 2) ? xv[r].z : xv[r].w;
                acc[r][0] = fmaf(xe, w0, acc[r][0]);
                acc[r][1] = fmaf(xe, w1, acc[r][1]);
            }
        }
    }

#pragma unroll
    for (int r = 0; r < 8; ++r) {
        int n = n0 + s * 8 + r;
        if (n < NN) {
            float dn = dinv[n];
            outb[n * HID + c]      = f2bf(acc[r][0] * dn);
            outb[n * HID + c + 32] = f2bf(acc[r][1] * dn);
        }
    }
}

// ---------------- pooling + head (bf16 input) ----------------
__global__ __launch_bounds__(256) void k_pool_head(const unsigned short* __restrict__ h,
                                                   const int* __restrict__ start,
                                                   const float* __restrict__ Wc, const float* __restrict__ bc,
                                                   float* __restrict__ out) {
    __shared__ float part[4][HID];
    int g = blockIdx.x;
    int tid = threadIdx.x;
    int j = tid & 63, w = tid >> 6;
    int beg = start[g], end = start[g + 1];
    float acc = 0.0f;
    for (int n = beg + w; n < end; n += 4) acc += bf2f(h[n * HID + j]);
    part[w][j] = acc;
    __syncthreads();
    if (w == 0) {
        float s = part[0][j] + part[1][j] + part[2][j] + part[3][j];
        float cnt = (float)(end - beg);
        float p = s / fmaxf(cnt, 1.0f);
#pragma unroll
        for (int c = 0; c < NC; ++c) {
            float v = p * Wc[j * NC + c];
            for (int off = 32; off > 0; off >>= 1) v += __shfl_down(v, off);
            if (j == 0) out[g * NC + c] = v + bc[c];
        }
    }
}

// ---------------- driver ----------------
extern "C" void kernel_launch(void* const* d_in, const int* in_sizes, int n_in,
                              void* d_out, int out_size, void* d_ws, size_t ws_size,
                              hipStream_t stream) {
    const float* x  = (const float*)d_in[0];
    const int* ei   = (const int*)d_in[1];
    const int* bat  = (const int*)d_in[2];
    const float* W1 = (const float*)d_in[3];
    const float* b1 = (const float*)d_in[4];
    const float* W2 = (const float*)d_in[5];
    const float* b2 = (const float*)d_in[6];
    const float* W3 = (const float*)d_in[7];
    const float* b3 = (const float*)d_in[8];
    const float* Wc = (const float*)d_in[9];
    const float* bc = (const float*)d_in[10];
    float* out = (float*)d_out;

    const int* src = ei;
    const int* dst = ei + NE;

    // workspace layout (bytes), all 16B-aligned; total ~36.9 MB
    char* wsb = (char*)d_ws;
    float* dinv         = (float*)wsb;                          // NN f32
    int*   row_ptr      = (int*)(wsb + 400000);                 // NN+1
    int*   srcs         = (int*)(wsb + 800016);                 // NE
    unsigned short* hWA = (unsigned short*)(wsb + 5600016);     // NN*HID bf16
    unsigned short* hWB = (unsigned short*)(wsb + 18400016);    // NN*HID bf16
    int*   cnt          = (int*)(wsb + 31200016);               // NN
    int*   exc          = (int*)(wsb + 31600016);               // NN
    int*   bsum         = (int*)(wsb + 32000016);               // 512
    int*   rank         = (int*)(wsb + 32002064);               // NE
    int*   start        = (int*)(wsb + 36802064);               // NG+1

    const int gE = (NE + 255) / 256;  // 4688

    // CSR build + normalization
    hipMemsetAsync(cnt, 0, NN * sizeof(int), stream);
    k_hist<<<gE, 256, 0, stream>>>(dst, cnt, rank);
    k_scan1<<<NB, 256, 0, stream>>>(cnt, exc, bsum, dinv);
    k_scan23<<<NB, 256, 0, stream>>>(exc, bsum, row_ptr);

    // bucket scatter + layer-1 GEMM + pool bounds, one grid (independent work)
    k_fused1<<<GB + G1 + NB, 256, 0, stream>>>(x, W1, dinv, hWA, src, dst, row_ptr, rank, srcs, bat, start);

    // layers (ping-pong bf16 buffers)
    k_aggregate<<<NN / 4, 256, 0, stream>>>(hWA, srcs, row_ptr, dinv, b1, hWB);
    k_gemm_bf<<<(NN + 63) / 64, 256, 0, stream>>>(hWB, W2, dinv, hWA);
    k_aggregate<<<NN / 4, 256, 0, stream>>>(hWA, srcs, row_ptr, dinv, b2, hWB);
    k_gemm_bf<<<(NN + 63) / 64, 256, 0, stream>>>(hWB, W3, dinv, hWA);
    k_aggregate<<<NN / 4, 256, 0, stream>>>(hWA, srcs, row_ptr, dinv, b3, hWB);

    // pooling + head
    k_pool_head<<<NG, 256, 0, stream>>>(hWB, start, Wc, bc, out);
}

// Round 10
// 343.566 us; speedup vs baseline: 1.0362x; 1.0362x over previous
//
#include <hip/hip_runtime.h>
#include <hip/hip_bf16.h>

#define NN 100000
#define NE 1200000
#define IND 128
#define HID 64
#define NC 5
#define NG 128
#define NB 391    // ceil(NN/256)
#define GB 1172   // bucket blocks (GB*256*4 >= NE)
#define G1 3125   // gemm1 blocks (NN/32)

typedef float v2f __attribute__((ext_vector_type(2)));

static __device__ __forceinline__ float bf2f(unsigned short u) {
    union { unsigned int i; float f; } x;
    x.i = (unsigned int)u << 16;
    return x.f;
}
static __device__ __forceinline__ unsigned short f2bf(float f) {
    union { float f; unsigned int i; } x;
    x.f = f;
    unsigned int r = (x.i + 0x7fffu + ((x.i >> 16) & 1u)) >> 16;  // RNE
    return (unsigned short)r;
}
// pack 2 f32 -> 2 fp8 (hardware, e4m3 on gfx950)
static __device__ __forceinline__ unsigned short f2fp8x2(float a, float b) {
    int p = __builtin_amdgcn_cvt_pk_fp8_f32(a, b, 0, false);
    return (unsigned short)(p & 0xffff);
}
// decode 4 fp8 (one uint) and accumulate into a0..a3
static __device__ __forceinline__ void fp8acc(unsigned int u, float& a0, float& a1, float& a2, float& a3) {
    v2f lo = __builtin_amdgcn_cvt_pk_f32_fp8(u, false);
    v2f hi = __builtin_amdgcn_cvt_pk_f32_fp8(u, true);
    a0 += lo.x; a1 += lo.y; a2 += hi.x; a3 += hi.y;
}

// ---------------- CSR build ----------------
__global__ __launch_bounds__(256) void k_hist(const int* __restrict__ dst, int* __restrict__ cnt,
                                              int* __restrict__ rank) {
    int e = blockIdx.x * 256 + threadIdx.x;
    if (e < NE) rank[e] = atomicAdd(&cnt[dst[e]], 1);
}

__global__ __launch_bounds__(256) void k_scan1(const int* __restrict__ cnt, int* __restrict__ exc,
                                               int* __restrict__ bsum, float* __restrict__ dinv) {
    __shared__ int lds[256];
    int tid = threadIdx.x;
    int i = blockIdx.x * 256 + tid;
    int v = (i < NN) ? cnt[i] : 0;
    lds[tid] = v;
    __syncthreads();
    for (int off = 1; off < 256; off <<= 1) {
        int t = (tid >= off) ? lds[tid - off] : 0;
        __syncthreads();
        lds[tid] += t;
        __syncthreads();
    }
    if (i < NN) {
        exc[i] = lds[tid] - v;
        dinv[i] = rsqrtf((float)v + 1.0f);
    }
    if (tid == 255) bsum[blockIdx.x] = lds[255];
}

__global__ __launch_bounds__(256) void k_scan23(const int* __restrict__ exc, const int* __restrict__ bsum,
                                                int* __restrict__ row_ptr) {
    __shared__ int lds[256];
    int tid = threadIdx.x;
    int me = blockIdx.x;
    int v = 0;
    if (tid < me) v = bsum[tid];
    if (tid + 256 < me) v += bsum[tid + 256];
    lds[tid] = v;
    __syncthreads();
    for (int off = 128; off > 0; off >>= 1) {
        if (tid < off) lds[tid] += lds[tid + off];
        __syncthreads();
    }
    int base = lds[0];
    int i = me * 256 + tid;
    if (i < NN) row_ptr[i] = exc[i] + base;
    if (i == 0) row_ptr[NN] = NE;
}

// ---------------- fused grid: bucket | layer-1 GEMM (fp8 out) | bounds ----------------
__global__ __launch_bounds__(256) void k_fused1(
    const float* __restrict__ X, const float* __restrict__ W,
    const float* __restrict__ dinv, unsigned short* __restrict__ out_f8,
    const int* __restrict__ src, const int* __restrict__ dst,
    const int* __restrict__ row_ptr, const int* __restrict__ rank,
    int* __restrict__ src_sorted,
    const int* __restrict__ batch, int* __restrict__ start)
{
    __shared__ float lds[IND * HID + 32 * IND];  // 48 KB (gemm1 segment only)
    int tid = threadIdx.x;

    if (blockIdx.x < GB) {
        int t = blockIdx.x * 256 + tid;
        const int T = GB * 256;
#pragma unroll
        for (int u = 0; u < 4; ++u) {
            int e = t + u * T;
            if (e < NE) src_sorted[row_ptr[dst[e]] + rank[e]] = src[e];
        }
        return;
    }
    if (blockIdx.x >= GB + G1) {
        int i = (blockIdx.x - GB - G1) * 256 + tid;
        if (i >= NN) return;
        int b = batch[i];
        if (i == 0) {
            for (int g = 0; g <= b; ++g) start[g] = 0;
        } else {
            int p = batch[i - 1];
            for (int g = p + 1; g <= b; ++g) start[g] = i;
        }
        if (i == NN - 1) {
            for (int g = b + 1; g <= NG; ++g) start[g] = NN;
        }
        return;
    }

    // ---- gemm1: thread owns adjacent cols {2c, 2c+1} for fp8 pair-packing ----
    float* Wl = lds;             // [128][64]
    float* xl = lds + IND * HID; // [32][128]
    int n0 = (blockIdx.x - GB) * 32;
    int c = tid & 31;
    int s = tid >> 5;

    {
        const float4* Wg = (const float4*)W;
        float4* Wl4 = (float4*)Wl;
#pragma unroll
        for (int i = 0; i < IND * 16 / 256; ++i) Wl4[i * 256 + tid] = Wg[i * 256 + tid];
    }
    {
        const float4* Xg = (const float4*)X;
        float4* xl4 = (float4*)xl;
        const float4 z = {0.f, 0.f, 0.f, 0.f};
#pragma unroll
        for (int i = 0; i < 32 * IND / 4 / 256; ++i) {
            int idx = i * 256 + tid;
            int node = n0 + idx / (IND / 4);
            xl4[idx] = (node < NN) ? Xg[(size_t)n0 * (IND / 4) + idx] : z;
        }
    }
    __syncthreads();

    float acc[4][2];
#pragma unroll
    for (int r = 0; r < 4; ++r) { acc[r][0] = 0.f; acc[r][1] = 0.f; }

#pragma unroll 4
    for (int k0 = 0; k0 < IND; k0 += 4) {
        float4 xv[4];
#pragma unroll
        for (int r = 0; r < 4; ++r) xv[r] = *(const float4*)&xl[(s * 4 + r) * IND + k0];
#pragma unroll
        for (int kk = 0; kk < 4; ++kk) {
            float w0 = Wl[(k0 + kk) * HID + 2 * c];
            float w1 = Wl[(k0 + kk) * HID + 2 * c + 1];
#pragma unroll
            for (int r = 0; r < 4; ++r) {
                float xe = (kk == 0) ? xv[r].x : (kk == 1) ? xv[r].y : (kk == 2) ? xv[r].z : xv[r].w;
                acc[r][0] = fmaf(xe, w0, acc[r][0]);
                acc[r][1] = fmaf(xe, w1, acc[r][1]);
            }
        }
    }

#pragma unroll
    for (int r = 0; r < 4; ++r) {
        int n = n0 + s * 4 + r;
        if (n < NN) {
            float dn = dinv[n];
            out_f8[(size_t)n * 32 + c] = f2fp8x2(acc[r][0] * dn, acc[r][1] * dn);
        }
    }
}

// ---------------- aggregate: fp8 gather, 4 edges per VMEM inst ----------------
// wave = 1 node; lane group grp=lane>>4 handles one edge; li=lane&15 -> 4 features.
// outb(bf16)[n][j] = bf16( relu(dinv[n]*(h[n][j] + sum_src h[src][j]) + b[j]) )
__global__ __launch_bounds__(256) void k_aggregate(const unsigned int* __restrict__ hW8,  // fp8 rows: 16 uints
                                                   const int* __restrict__ srcs,
                                                   const int* __restrict__ row_ptr,
                                                   const float* __restrict__ dinv,
                                                   const float* __restrict__ b,
                                                   unsigned int* __restrict__ outb) {    // bf16 rows: 32 uints
    int tid = threadIdx.x;
    int lane = tid & 63;
    int grp = lane >> 4;
    int li = lane & 15;
    int n = blockIdx.x * 4 + (tid >> 6);  // NN % 4 == 0

    float a0 = 0.f, a1 = 0.f, a2 = 0.f, a3 = 0.f;
    if (grp == 0) {  // self term once
        unsigned int su = hW8[(size_t)n * 16 + li];
        fp8acc(su, a0, a1, a2, a3);
    }

    int e = row_ptr[n];
    int end = row_ptr[n + 1];

    // 8 edges per iter, 2 gather insts in flight (each covering 4 edges)
    for (; e + 7 < end; e += 8) {
        int sA = srcs[e + grp];
        int sB = srcs[e + 4 + grp];
        unsigned int uA = hW8[(size_t)sA * 16 + li];
        unsigned int uB = hW8[(size_t)sB * 16 + li];
        fp8acc(uA, a0, a1, a2, a3);
        fp8acc(uB, a0, a1, a2, a3);
    }
    if (e + 3 < end) {
        int sA = srcs[e + grp];
        unsigned int uA = hW8[(size_t)sA * 16 + li];
        fp8acc(uA, a0, a1, a2, a3);
        e += 4;
    }
    int rem = end - e;  // 0..3
    if (grp < rem) {
        int sA = srcs[e + grp];
        unsigned int uA = hW8[(size_t)sA * 16 + li];
        fp8acc(uA, a0, a1, a2, a3);
    }

    // reduce across the 4 groups
    a0 += __shfl_xor(a0, 16, 64);
    a1 += __shfl_xor(a1, 16, 64);
    a2 += __shfl_xor(a2, 16, 64);
    a3 += __shfl_xor(a3, 16, 64);
    a0 += __shfl_xor(a0, 32, 64);
    a1 += __shfl_xor(a1, 32, 64);
    a2 += __shfl_xor(a2, 32, 64);
    a3 += __shfl_xor(a3, 32, 64);

    if (lane < 16) {
        float dn = dinv[n];
        float4 bv = ((const float4*)b)[li];
        float v0 = fmaxf(fmaf(dn, a0, bv.x), 0.0f);
        float v1 = fmaxf(fmaf(dn, a1, bv.y), 0.0f);
        float v2 = fmaxf(fmaf(dn, a2, bv.z), 0.0f);
        float v3 = fmaxf(fmaf(dn, a3, bv.w), 0.0f);
        uint2 p;
        p.x = (unsigned int)f2bf(v0) | ((unsigned int)f2bf(v1) << 16);
        p.y = (unsigned int)f2bf(v2) | ((unsigned int)f2bf(v3) << 16);
        ((uint2*)outb)[(size_t)n * 16 + li] = p;
    }
}

// ---------------- GEMM layers 2/3: bf16 in, fp8 out ----------------
__global__ __launch_bounds__(256) void k_gemm_bf(const unsigned short* __restrict__ X,
                                                 const float* __restrict__ W,
                                                 const float* __restrict__ dinv,
                                                 unsigned short* __restrict__ out_f8) {
    __shared__ float Wl[HID * HID];  // 16 KB
    __shared__ float xl[64 * HID];   // 16 KB
    int tid = threadIdx.x;
    int n0 = blockIdx.x * 64;

    {
        const float4* Wg = (const float4*)W;
        float4* Wl4 = (float4*)Wl;
#pragma unroll
        for (int i = 0; i < HID * HID / 4 / 256; ++i) Wl4[i * 256 + tid] = Wg[i * 256 + tid];
    }
    {
        const uint4* Xg = (const uint4*)X;
#pragma unroll
        for (int i = 0; i < 2; ++i) {
            int idx = i * 256 + tid;      // 0..511
            int ln = idx >> 3;            // local node
            int k0 = (idx & 7) * 8;
            int node = n0 + ln;
            float f[8];
            if (node < NN) {
                uint4 u = Xg[(size_t)n0 * 8 + idx];
                f[0] = bf2f((unsigned short)(u.x & 0xffff));
                f[1] = bf2f((unsigned short)(u.x >> 16));
                f[2] = bf2f((unsigned short)(u.y & 0xffff));
                f[3] = bf2f((unsigned short)(u.y >> 16));
                f[4] = bf2f((unsigned short)(u.z & 0xffff));
                f[5] = bf2f((unsigned short)(u.z >> 16));
                f[6] = bf2f((unsigned short)(u.w & 0xffff));
                f[7] = bf2f((unsigned short)(u.w >> 16));
            } else {
#pragma unroll
                for (int q = 0; q < 8; ++q) f[q] = 0.f;
            }
#pragma unroll
            for (int q = 0; q < 8; ++q) xl[ln * HID + k0 + q] = f[q];
        }
    }
    __syncthreads();

    int c = tid & 31;
    int s = tid >> 5;
    float acc[8][2];
#pragma unroll
    for (int r = 0; r < 8; ++r) { acc[r][0] = 0.f; acc[r][1] = 0.f; }

#pragma unroll 4
    for (int k0 = 0; k0 < HID; k0 += 4) {
        float4 xv[8];
#pragma unroll
        for (int r = 0; r < 8; ++r) xv[r] = *(const float4*)&xl[(s * 8 + r) * HID + k0];
#pragma unroll
        for (int kk = 0; kk < 4; ++kk) {
            float w0 = Wl[(k0 + kk) * HID + 2 * c];
            float w1 = Wl[(k0 + kk) * HID + 2 * c + 1];
#pragma unroll
            for (int r = 0; r < 8; ++r) {
                float xe = (kk == 0) ? xv[r].x : (kk == 1) ? xv[r].y : (kk == 2) ? xv[r].z : xv[r].w;
                acc[r][0] = fmaf(xe, w0, acc[r][0]);
                acc[r][1] = fmaf(xe, w1, acc[r][1]);
            }
        }
    }

#pragma unroll
    for (int r = 0; r < 8; ++r) {
        int n = n0 + s * 8 + r;
        if (n < NN) {
            float dn = dinv[n];
            out_f8[(size_t)n * 32 + c] = f2fp8x2(acc[r][0] * dn, acc[r][1] * dn);
        }
    }
}

// ---------------- pooling + head (bf16 input) ----------------
__global__ __launch_bounds__(256) void k_pool_head(const unsigned short* __restrict__ h,
                                                   const int* __restrict__ start,
                                                   const float* __restrict__ Wc, const float* __restrict__ bc,
                                                   float* __restrict__ out) {
    __shared__ float part[4][HID];
    int g = blockIdx.x;
    int tid = threadIdx.x;
    int j = tid & 63, w = tid >> 6;
    int beg = start[g], end = start[g + 1];
    float acc = 0.0f;
    for (int n = beg + w; n < end; n += 4) acc += bf2f(h[n * HID + j]);
    part[w][j] = acc;
    __syncthreads();
    if (w == 0) {
        float s = part[0][j] + part[1][j] + part[2][j] + part[3][j];
        float cnt = (float)(end - beg);
        float p = s / fmaxf(cnt, 1.0f);
#pragma unroll
        for (int c = 0; c < NC; ++c) {
            float v = p * Wc[j * NC + c];
            for (int off = 32; off > 0; off >>= 1) v += __shfl_down(v, off);
            if (j == 0) out[g * NC + c] = v + bc[c];
        }
    }
}

// ---------------- driver ----------------
extern "C" void kernel_launch(void* const* d_in, const int* in_sizes, int n_in,
                              void* d_out, int out_size, void* d_ws, size_t ws_size,
                              hipStream_t stream) {
    const float* x  = (const float*)d_in[0];
    const int* ei   = (const int*)d_in[1];
    const int* bat  = (const int*)d_in[2];
    const float* W1 = (const float*)d_in[3];
    const float* b1 = (const float*)d_in[4];
    const float* W2 = (const float*)d_in[5];
    const float* b2 = (const float*)d_in[6];
    const float* W3 = (const float*)d_in[7];
    const float* b3 = (const float*)d_in[8];
    const float* Wc = (const float*)d_in[9];
    const float* bc = (const float*)d_in[10];
    float* out = (float*)d_out;

    const int* src = ei;
    const int* dst = ei + NE;

    // workspace layout (bytes), all 16B-aligned
    char* wsb = (char*)d_ws;
    float* dinv         = (float*)wsb;                          // NN f32
    int*   row_ptr      = (int*)(wsb + 400000);                 // NN+1
    int*   srcs         = (int*)(wsb + 800016);                 // NE
    unsigned short* hF8 = (unsigned short*)(wsb + 5600016);     // NN*HID fp8 (6.4 MB, ushort-pair packed)
    unsigned short* hBF = (unsigned short*)(wsb + 18400016);    // NN*HID bf16 (12.8 MB)
    int*   cnt          = (int*)(wsb + 31200016);               // NN
    int*   exc          = (int*)(wsb + 31600016);               // NN
    int*   bsum         = (int*)(wsb + 32000016);               // 512
    int*   rank         = (int*)(wsb + 32002064);               // NE
    int*   start        = (int*)(wsb + 36802064);               // NG+1

    const int gE = (NE + 255) / 256;  // 4688

    // CSR build + normalization
    hipMemsetAsync(cnt, 0, NN * sizeof(int), stream);
    k_hist<<<gE, 256, 0, stream>>>(dst, cnt, rank);
    k_scan1<<<NB, 256, 0, stream>>>(cnt, exc, bsum, dinv);
    k_scan23<<<NB, 256, 0, stream>>>(exc, bsum, row_ptr);

    // bucket scatter + layer-1 GEMM (fp8 out) + pool bounds, one grid
    k_fused1<<<GB + G1 + NB, 256, 0, stream>>>(x, W1, dinv, hF8, src, dst, row_ptr, rank, srcs, bat, start);

    // layers: gemm writes fp8 (gathered), aggregate writes bf16 (streamed)
    k_aggregate<<<NN / 4, 256, 0, stream>>>((const unsigned int*)hF8, srcs, row_ptr, dinv, b1, (unsigned int*)hBF);
    k_gemm_bf<<<(NN + 63) / 64, 256, 0, stream>>>(hBF, W2, dinv, hF8);
    k_aggregate<<<NN / 4, 256, 0, stream>>>((const unsigned int*)hF8, srcs, row_ptr, dinv, b2, (unsigned int*)hBF);
    k_gemm_bf<<<(NN + 63) / 64, 256, 0, stream>>>(hBF, W3, dinv, hF8);
    k_aggregate<<<NN / 4, 256, 0, stream>>>((const unsigned int*)hF8, srcs, row_ptr, dinv, b3, (unsigned int*)hBF);

    // pooling + head
    k_pool_head<<<NG, 256, 0, stream>>>(hBF, start, Wc, bc, out);
}